// Round 22
// baseline (161.667 us; speedup 1.0000x reference)
//
#include <hip/hip_runtime.h>
#include <cstdint>
#include <cstddef>

typedef _Float16 f16;
typedef _Float16 f16x2 __attribute__((ext_vector_type(2)));
typedef _Float16 f16x4 __attribute__((ext_vector_type(4)));
typedef _Float16 f16x8 __attribute__((ext_vector_type(8)));
typedef float f32x4 __attribute__((ext_vector_type(4)));
typedef float f32x16 __attribute__((ext_vector_type(16)));

#define DEVI __device__ __forceinline__

DEVI void gload_lds16(const void* g, void* l) {
  __builtin_amdgcn_global_load_lds(
      (const __attribute__((address_space(1))) void*)g,
      (__attribute__((address_space(3))) void*)l, 16, 0, 0);
}

DEVI float fexp2(float x) { return __builtin_amdgcn_exp2f(x); }

DEVI float fdot2u(unsigned a, unsigned b, float c) {
  return __builtin_amdgcn_fdot2(__builtin_bit_cast(f16x2, a),
                                __builtin_bit_cast(f16x2, b), c, false);
}
#define ONES2 0x3C003C00u  // (f16)1.0 x2

// ------------- fused prep: x cvt + 4 weight cvt + sctab + pmask ----------
__global__ void k_prep(const float* __restrict__ x,
                       const float* __restrict__ w0, const float* __restrict__ w1,
                       const float* __restrict__ w2, const float* __restrict__ w3,
                       f16* __restrict__ xb,
                       f16* __restrict__ o0, f16* __restrict__ o1,
                       f16* __restrict__ o2, f16* __restrict__ o3,
                       const int* __restrict__ amask,
                       const int* __restrict__ pE, const int* __restrict__ pSkip,
                       float2* __restrict__ sctab, unsigned* __restrict__ pmask) {
  int bb = blockIdx.x;
  if (bb < 4096) {
    int i = (bb * 256 + threadIdx.x) * 8;
    const float4* p = reinterpret_cast<const float4*>(x + i);
    float4 a = p[0], b = p[1];
    f16x8 o;
    o[0] = (f16)a.x; o[1] = (f16)a.y; o[2] = (f16)a.z; o[3] = (f16)a.w;
    o[4] = (f16)b.x; o[5] = (f16)b.y; o[6] = (f16)b.z; o[7] = (f16)b.w;
    *reinterpret_cast<f16x8*>(xb + i) = o;
  } else if (bb < 6144) {
    int seg = (bb - 4096) >> 9;
    const float* in = (seg == 0) ? w0 : (seg == 1) ? w1 : (seg == 2) ? w2 : w3;
    f16* out = (seg == 0) ? o0 : (seg == 1) ? o1 : (seg == 2) ? o2 : o3;
    int i = (((bb - 4096) & 511) * 256 + threadIdx.x) * 8;
    const float4* p = reinterpret_cast<const float4*>(in + i);
    float4 a = p[0], b = p[1];
    f16x8 o;
    o[0] = (f16)a.x; o[1] = (f16)a.y; o[2] = (f16)a.z; o[3] = (f16)a.w;
    o[4] = (f16)b.x; o[5] = (f16)b.y; o[6] = (f16)b.z; o[7] = (f16)b.w;
    *reinterpret_cast<f16x8*>(out + i) = o;
  } else if (bb < 6400) {
    int E = *pE, skip = *pSkip;
    int idx = (bb - 6144) * 256 + threadIdx.x;
    int s = idx >> 5, t = idx & 31;
    float c = 1.0f, sn = 0.0f;
    if (!(skip && s < E)) {
      int p = skip ? s - E : s;
      float inv_freq = powf(10000.0f, -(float)t / 32.0f);
      sincosf((float)p * inv_freq, &sn, &c);
    }
    sctab[idx] = make_float2(c, sn);
  } else {
    int tid = threadIdx.x;
    int b = tid >> 6, jb = tid & 63;
    unsigned bits = 0;
    for (int j = 0; j < 32; ++j)
      bits |= (amask[b * 2048 + jb * 32 + j] != 0 ? 1u : 0u) << j;
    pmask[tid] = bits;
  }
}

// ---------------- GEMM: C[M,N] = A[M,K] * B[N,K]^T ----------------
// BK=64, 2 LDS buffers = 64 KB, counted-vmcnt depth-1 (r16-exact).
template<int MODE>
__global__ __launch_bounds__(256) void k_gemm(
    const f16* __restrict__ A,
    const f16* __restrict__ B0, const f16* __restrict__ B1, const f16* __restrict__ B2,
    void* __restrict__ C0, void* __restrict__ C1, void* __restrict__ C2,
    const float2* __restrict__ sctab) {
  constexpr int K = 1024, N = 1024;
  __shared__ char smem[65536];
  const int lid = blockIdx.x;
  const int xcd = lid & 7;
  int z, mp, n;
  if (MODE == 1) {
    int c = lid >> 3;
    mp = xcd * 8 + (c & 7);
    n = c >> 3;
    z = 0;
  } else {
    int c = lid >> 3;
    mp = xcd * 8 + (c & 7);
    n = (c >> 3) & 7;
    z = c >> 6;
  }
  const f16* B = (z == 0) ? B0 : ((z == 1) ? B1 : B2);
  const int tid = threadIdx.x;
  const int lane = tid & 63;
  const int wave = tid >> 6;
  const int wr = wave >> 1, wc = wave & 1;
  const int l15 = lane & 15, l4 = lane >> 4;
  const int m0 = mp * 128, n0 = n * 128;

  const int sr = tid >> 3, su = tid & 7;
  const int ce = (su ^ (sr & 7)) * 8;
  const f16* gA0 = A + (size_t)(m0 + sr) * K + ce;
  const f16* gB0 = B + (size_t)(n0 + sr) * K + ce;

  auto STAGE = [&](int bb, int kt) {
#pragma unroll
    for (int k = 0; k < 4; ++k)
      gload_lds16(gA0 + kt + (size_t)(32 * k) * K,
                  smem + bb * 16384 + k * 4096 + tid * 16);
#pragma unroll
    for (int k = 0; k < 4; ++k)
      gload_lds16(gB0 + kt + (size_t)(32 * k) * K,
                  smem + 32768 + bb * 16384 + k * 4096 + tid * 16);
  };

  f32x4 acc[4][4] = {};

  STAGE(0, 0);
  for (int t = 0; t < 16; ++t) {
    const int cur = t & 1;
    if (t + 1 < 16) {
      STAGE(cur ^ 1, (t + 1) * 64);
      asm volatile("s_waitcnt vmcnt(8)" ::: "memory");
    } else {
      asm volatile("s_waitcnt vmcnt(0)" ::: "memory");
    }
    __builtin_amdgcn_s_barrier();
    __builtin_amdgcn_sched_barrier(0);
#pragma unroll
    for (int kk = 0; kk < 2; ++kk) {
      f16x8 af[4], bf[4];
#pragma unroll
      for (int mi = 0; mi < 4; ++mi) {
        int r = wr * 64 + mi * 16 + l15;
        af[mi] = *reinterpret_cast<const f16x8*>(
            smem + cur * 16384 + r * 128 + (((kk * 4 + l4) ^ (r & 7)) * 16));
      }
#pragma unroll
      for (int ni = 0; ni < 4; ++ni) {
        int r = wc * 64 + ni * 16 + l15;
        bf[ni] = *reinterpret_cast<const f16x8*>(
            smem + 32768 + cur * 16384 + r * 128 + (((kk * 4 + l4) ^ (r & 7)) * 16));
      }
#pragma unroll
      for (int mi = 0; mi < 4; ++mi)
#pragma unroll
        for (int ni = 0; ni < 4; ++ni)
          acc[mi][ni] = __builtin_amdgcn_mfma_f32_16x16x32_f16(af[mi], bf[ni], acc[mi][ni], 0, 0, 0);
    }
  }

  if (MODE == 1) {
#pragma unroll
    for (int mi = 0; mi < 4; ++mi)
#pragma unroll
      for (int ni = 0; ni < 4; ++ni)
#pragma unroll
        for (int r = 0; r < 4; ++r) {
          int row = m0 + wr * 64 + mi * 16 + l4 * 4 + r;
          int col = n0 + wc * 64 + ni * 16 + l15;
          ((float*)C0)[(size_t)row * N + col] = acc[mi][ni][r];
        }
    return;
  }

  f16* Qf = (f16*)C0;
  f16* Kx = (f16*)C1;
  f16* Vx = (f16*)C2;

  if (z == 0) {
#pragma unroll
    for (int mi = 0; mi < 4; ++mi)
#pragma unroll
      for (int ni = 0; ni < 4; ++ni)
#pragma unroll
        for (int r = 0; r < 4; ++r) {
          int row = m0 + wr * 64 + mi * 16 + l4 * 4 + r;
          int col = n0 + wc * 64 + ni * 16 + l15;
          int s = row & 2047;
          int dd = col & 63;
          float val = acc[mi][ni][r];
          float pv = __shfl_xor(val, 1, 64);
          float2 cs = sctab[s * 32 + (dd >> 1)];
          val = val * cs.x + ((l15 & 1) ? pv * cs.y : -pv * cs.y);
          Qf[(size_t)row * 1024 + col] = (f16)val;
        }
    return;
  }

  __syncthreads();  // all loads landed; reuse smem as C-tile
  f16* Ct = (f16*)smem;

  if (z == 1) {
#pragma unroll
    for (int mi = 0; mi < 4; ++mi)
#pragma unroll
      for (int ni = 0; ni < 4; ++ni)
#pragma unroll
        for (int r = 0; r < 4; ++r) {
          int sl = wr * 64 + mi * 16 + l4 * 4 + r;
          int cl = wc * 64 + ni * 16 + l15;
          int s = (m0 + sl) & 2047;
          float val = acc[mi][ni][r];
          float pv = __shfl_xor(val, 1, 64);
          float2 cs = sctab[s * 32 + ((cl & 63) >> 1)];
          val = val * cs.x + ((l15 & 1) ? pv * cs.y : -pv * cs.y);
          *(f16*)((char*)Ct + sl * 256 + (((cl >> 3) ^ (sl & 15)) << 4) + (cl & 7) * 2) = (f16)val;
        }
    __syncthreads();
#pragma unroll
    for (int it = 0; it < 8; ++it) {
      int it2 = wave * 8 + it;
      int h2 = it2 >> 4, k16 = (it2 >> 2) & 3, hf = (it2 >> 1) & 1, sh = it2 & 1;
      int sl = sh * 64 + lane;
      int cl = h2 * 64 + k16 * 16 + hf * 8;
      f16x8 v = *(const f16x8*)((const char*)Ct + sl * 256 + (((cl >> 3) ^ (sl & 15)) << 4));
      int sg = m0 + sl;
      int b = sg >> 11, s = sg & 2047;
      int h = (n0 >> 6) + h2;
      *reinterpret_cast<f16x8*>(
          Kx + (((size_t)((b * 16 + h) * 4 + k16) * 2048 + s) << 4) + hf * 8) = v;
    }
  } else {
#pragma unroll
    for (int mi = 0; mi < 4; ++mi)
#pragma unroll
      for (int ni = 0; ni < 4; ++ni) {
        int sl = wr * 64 + mi * 16 + l4 * 4;
        int cl = wc * 64 + ni * 16 + l15;
        f16x4 pk;
#pragma unroll
        for (int r = 0; r < 4; ++r) pk[r] = (f16)acc[mi][ni][r];
        *(f16x4*)((char*)Ct + cl * 256 + ((((sl >> 2) ^ (cl & 31))) << 3)) = pk;
      }
    __syncthreads();
#pragma unroll
    for (int it = 0; it < 8; ++it) {
      int it2 = wave * 8 + it;
      int hh = it2 >> 4, dh2 = (it2 >> 3) & 1, kvb = (it2 >> 1) & 3, hf = it2 & 1;
      int kh = lane >> 5, ql = lane & 31;
      int cl = hh * 64 + dh2 * 32 + ql;
      int s0 = kvb * 32 + kh * 16 + hf * 4;
      f16x4 a = *(const f16x4*)((const char*)Ct + cl * 256 + (((s0 >> 2) ^ (cl & 31)) << 3));
      f16x4 c = *(const f16x4*)((const char*)Ct + cl * 256 + ((((s0 + 8) >> 2) ^ (cl & 31)) << 3));
      f16x8 v;
#pragma unroll
      for (int e = 0; e < 4; ++e) { v[e] = a[e]; v[4 + e] = c[e]; }
      int b = m0 >> 11;
      int kvblk = ((m0 & 2047) >> 5) + kvb;
      int h = (n0 >> 6) + hh;
      size_t idx = (((size_t)(((b * 16 + h) * 64 + kvblk) * 2 + dh2) * 2 + kh) * 32 + ql) << 4;
      *reinterpret_cast<f16x8*>(Vx + idx + hf * 8) = v;
    }
  }
}

// ---------------- flash attention: 8-wave Q-group, LDS-shared K/V --------
// Grid 256 x 512 = 64 bh x 4 gp; PHASE(7-gp) then PHASE(gp); 72 staged
// tiles/block uniform. Conflict-free linear LDS (pre-swizzled global src),
// T5 setprio. DEPTH-2 staging (r21 was depth-1): 3 x 8KB buffers, iter jb
// stages jb+2 then vmcnt(2) -> tile-jb landed, jb+1/jb+2 in flight ACROSS
// the barrier (T4; same schedule that fixed the GEMM in r13). WAR margin:
// last reads of a buffer complete ~150cy after its barrier, overwrite
// lands >=700cy after.
__global__ __launch_bounds__(512) void k_attn(
    const f16* __restrict__ Q, const f16* __restrict__ Kx, const f16* __restrict__ Vx,
    const unsigned* __restrict__ pmask, const int* __restrict__ pE,
    f16* __restrict__ AO) {
  __shared__ char smem[24576];   // 3 x [K 4KB | V 4KB]
  const int lid = (blockIdx.x & 7) * 32 + (blockIdx.x >> 3);  // XCD swizzle (256%8==0)
  const int bh = lid >> 2;                                    // 8 bh per XCD
  const int gp = lid & 3;
  const int tid = threadIdx.x;
  const int wave = tid >> 6;
  const int lane = tid & 63;
  const int ql = lane & 31;
  const int hf = lane >> 5;
  const int b = bh >> 4, h = bh & 15;
  const int E = *pE;
  const int ekv = (E + 31) >> 5;
  constexpr float SCALE = 0.125f * 1.44269504088896f;  // dh^-0.5 * log2(e)

  // staging: thread t fetches global unit u(lp)=(lp&31)*2+(lp>>5) of its
  // plane into linear LDS unit t -> fragment reads at lane*16, conflict-free.
  const char* sbase;
  int sstride, dstoff;
  {
    int lp = tid & 63;
    int su = ((lp & 31) * 2 + (lp >> 5)) * 16;
    if (tid < 256) {             // K: plane = tid>>6 (k16), 1KB/plane/jb
      int plane = tid >> 6;
      sbase = (const char*)Kx + ((size_t)(bh * 4 + plane) << 16) + su;
      sstride = 1024;
      dstoff = tid * 16;         // [0, 4096)
    } else {                     // V: plane = c (0..3), 1KB/plane, 4KB/jb
      int vt = tid - 256;
      int plane = vt >> 6;
      sbase = (const char*)Vx + (size_t)(bh * 64) * 4096 + plane * 1024 + su;
      sstride = 4096;
      dstoff = 4096 + vt * 16;   // [4096, 8192)
    }
  }

  auto STAGE = [&](int buf, int jb) {
    gload_lds16(sbase + (size_t)jb * sstride, smem + buf * 8192 + dstoff);
  };

  auto PHASE = [&](int G) {
    const int qt = 8 * G + wave;
    const int irow = qt * 32 + ql;
    int nkv_own = qt + 1;
    if (ekv > nkv_own) nkv_own = ekv;
    if (nkv_own > 64) nkv_own = 64;
    int nkv_blk = 8 * G + 8;
    if (ekv > nkv_blk) nkv_blk = ekv;
    if (nkv_blk > 64) nkv_blk = 64;

    f16x8 qf[4];
    {
      const f16* qp = Q + ((size_t)(b * 2048 + irow)) * 1024 + h * 64 + hf * 8;
#pragma unroll
      for (int k16 = 0; k16 < 4; ++k16) {
        f16x8 v = *reinterpret_cast<const f16x8*>(qp + k16 * 16);
#pragma unroll
        for (int e = 0; e < 8; ++e) v[e] = (f16)((float)v[e] * SCALE);
        qf[k16] = v;
      }
    }

    f32x16 acc0 = {}, acc1 = {};
    float mq = -1e30f, lq = 0.f;

    STAGE(0, 0);
    if (nkv_blk > 1) STAGE(1, 1);
    for (int jb = 0; jb < nkv_blk; ++jb) {
      const int buf = jb % 3;
      if (jb + 2 < nkv_blk) {
        STAGE((jb + 2) % 3, jb + 2);
        asm volatile("s_waitcnt vmcnt(2)" ::: "memory");
      } else if (jb + 1 < nkv_blk) {
        asm volatile("s_waitcnt vmcnt(1)" ::: "memory");
      } else {
        asm volatile("s_waitcnt vmcnt(0)" ::: "memory");
      }
      __builtin_amdgcn_s_barrier();
      __builtin_amdgcn_sched_barrier(0);
      if (jb < nkv_own) {
        const char* Ks = smem + buf * 8192;
        const char* Vs = Ks + 4096;
        __builtin_amdgcn_s_setprio(1);
        f32x16 st = {};
#pragma unroll
        for (int k16 = 0; k16 < 4; ++k16) {
          f16x8 kf = *reinterpret_cast<const f16x8*>(Ks + k16 * 1024 + lane * 16);
          st = __builtin_amdgcn_mfma_f32_32x32x16_f16(kf, qf[k16], st, 0, 0, 0);
        }
        __builtin_amdgcn_s_setprio(0);
        f16x8 vf[4];
#pragma unroll
        for (int c = 0; c < 4; ++c)
          vf[c] = *reinterpret_cast<const f16x8*>(Vs + c * 1024 + lane * 16);
        unsigned pm = pmask[b * 64 + jb];
        bool full = ((jb < qt) || ((jb + 1) * 32 <= E)) && (pm == 0xffffffffu);
        if (!full) {
#pragma unroll
          for (int r = 0; r < 16; ++r) {
            int kvl = (r & 3) + 8 * (r >> 2) + 4 * hf;
            int jcol = jb * 32 + kvl;
            bool vis = ((jcol <= irow) || (jcol < E)) && (((pm >> kvl) & 1u) != 0);
            st[r] = vis ? st[r] : -1e30f;
          }
        }
        float t0 = fmaxf(fmaxf(st[0], st[1]), st[2]);
        float t1 = fmaxf(fmaxf(st[3], st[4]), st[5]);
        float t2 = fmaxf(fmaxf(st[6], st[7]), st[8]);
        float t3 = fmaxf(fmaxf(st[9], st[10]), st[11]);
        float t4 = fmaxf(fmaxf(st[12], st[13]), st[14]);
        float mt = fmaxf(fmaxf(t0, t1), t2);
        mt = fmaxf(fmaxf(mt, t3), fmaxf(t4, st[15]));
        mt = fmaxf(mt, __shfl_xor(mt, 32, 64));
        if (!__all(mt - mq <= 8.0f)) {
          float mnew = fmaxf(mq, mt);
          float alpha = fexp2(mq - mnew);
          lq *= alpha;
#pragma unroll
          for (int r = 0; r < 16; ++r) { acc0[r] *= alpha; acc1[r] *= alpha; }
          mq = mnew;
        }
        union PF { unsigned u[4]; f16x8 v; } pf0, pf1;
#pragma unroll
        for (int t = 0; t < 4; ++t) {
          pf0.u[t] = __builtin_bit_cast(unsigned, __builtin_amdgcn_cvt_pkrtz(
              fexp2(st[2 * t] - mq), fexp2(st[2 * t + 1] - mq)));
          pf1.u[t] = __builtin_bit_cast(unsigned, __builtin_amdgcn_cvt_pkrtz(
              fexp2(st[8 + 2 * t] - mq), fexp2(st[9 + 2 * t] - mq)));
        }
        float ps = 0.f;
#pragma unroll
        for (int t = 0; t < 4; ++t) {
          ps = fdot2u(pf0.u[t], ONES2, ps);
          ps = fdot2u(pf1.u[t], ONES2, ps);
        }
        lq += ps;
        __builtin_amdgcn_s_setprio(1);
        acc0 = __builtin_amdgcn_mfma_f32_32x32x16_f16(vf[0], pf0.v, acc0, 0, 0, 0);
        acc0 = __builtin_amdgcn_mfma_f32_32x32x16_f16(vf[1], pf1.v, acc0, 0, 0, 0);
        acc1 = __builtin_amdgcn_mfma_f32_32x32x16_f16(vf[2], pf0.v, acc1, 0, 0, 0);
        acc1 = __builtin_amdgcn_mfma_f32_32x32x16_f16(vf[3], pf1.v, acc1, 0, 0, 0);
        __builtin_amdgcn_s_setprio(0);
      }
    }

    float ltot = lq + __shfl_xor(lq, 32, 64);
    float inv = 1.0f / ltot;
    f16* op = AO + ((size_t)(b * 2048 + irow)) * 1024 + h * 64;
#pragma unroll
    for (int t = 0; t < 4; ++t) {
      int d0 = 8 * t + 4 * hf;
      f16x4 o0, o1;
#pragma unroll
      for (int e = 0; e < 4; ++e) {
        o0[e] = (f16)(acc0[4 * t + e] * inv);
        o1[e] = (f16)(acc1[4 * t + e] * inv);
      }
      *reinterpret_cast<f16x4*>(op + d0) = o0;
      *reinterpret_cast<f16x4*>(op + 32 + d0) = o1;
    }
    __builtin_amdgcn_s_barrier();  // protect LDS buffers before next phase
  };

  PHASE(7 - gp);   // heavy group first
  PHASE(gp);       // light group
}

// ---------------- launcher ----------------
extern "C" void kernel_launch(void* const* d_in, const int* in_sizes, int n_in,
                              void* d_out, int out_size, void* d_ws, size_t ws_size,
                              hipStream_t stream) {
  const float* x  = (const float*)d_in[0];
  const float* Wq = (const float*)d_in[1];
  const float* Wk = (const float*)d_in[2];
  const float* Wv = (const float*)d_in[3];
  const float* Wo = (const float*)d_in[4];
  const int* amask = (const int*)d_in[5];
  const int* pE    = (const int*)d_in[6];
  const int* pSkip = (const int*)d_in[7];

  char* ws = (char*)d_ws;
  f16* xb   = (f16*)(ws);
  f16* Wqb  = (f16*)(ws + (16u << 20));
  f16* Wkb  = (f16*)(ws + (18u << 20));
  f16* Wvb  = (f16*)(ws + (20u << 20));
  f16* Wob  = (f16*)(ws + (22u << 20));
  f16* Qf   = (f16*)(ws + (24u << 20));
  f16* Kx   = (f16*)(ws + (40u << 20));
  f16* Vx   = (f16*)(ws + (56u << 20));
  float2* sctab = (float2*)(ws + (72u << 20));
  unsigned* pmask = (unsigned*)(ws + (73u << 20));
  f16* AO   = xb;

  k_prep<<<6401, 256, 0, stream>>>(x, Wq, Wk, Wv, Wo, xb, Wqb, Wkb, Wvb, Wob,
                                   amask, pE, pSkip, sctab, pmask);
  k_gemm<2><<<1536, 256, 0, stream>>>(xb, Wqb, Wkb, Wvb, Qf, Kx, Vx, sctab);
  k_attn<<<256, 512, 0, stream>>>(Qf, Kx, Vx, pmask, pE, AO);
  k_gemm<1><<<512, 256, 0, stream>>>(AO, Wob, Wob, Wob, d_out, d_out, d_out, nullptr);
}

// Round 24
// 154.842 us; speedup vs baseline: 1.0441x; 1.0441x over previous
//
#include <hip/hip_runtime.h>
#include <cstdint>
#include <cstddef>

typedef _Float16 f16;
typedef _Float16 f16x2 __attribute__((ext_vector_type(2)));
typedef _Float16 f16x4 __attribute__((ext_vector_type(4)));
typedef _Float16 f16x8 __attribute__((ext_vector_type(8)));
typedef float f32x4 __attribute__((ext_vector_type(4)));
typedef float f32x16 __attribute__((ext_vector_type(16)));

#define DEVI __device__ __forceinline__

DEVI void gload_lds16(const void* g, void* l) {
  __builtin_amdgcn_global_load_lds(
      (const __attribute__((address_space(1))) void*)g,
      (__attribute__((address_space(3))) void*)l, 16, 0, 0);
}

DEVI float fexp2(float x) { return __builtin_amdgcn_exp2f(x); }

DEVI float fdot2u(unsigned a, unsigned b, float c) {
  return __builtin_amdgcn_fdot2(__builtin_bit_cast(f16x2, a),
                                __builtin_bit_cast(f16x2, b), c, false);
}
#define ONES2 0x3C003C00u  // (f16)1.0 x2

// ------------- fused prep: x cvt + 4 weight cvt + sctab + pmask ----------
__global__ void k_prep(const float* __restrict__ x,
                       const float* __restrict__ w0, const float* __restrict__ w1,
                       const float* __restrict__ w2, const float* __restrict__ w3,
                       f16* __restrict__ xb,
                       f16* __restrict__ o0, f16* __restrict__ o1,
                       f16* __restrict__ o2, f16* __restrict__ o3,
                       const int* __restrict__ amask,
                       const int* __restrict__ pE, const int* __restrict__ pSkip,
                       float2* __restrict__ sctab, unsigned* __restrict__ pmask) {
  int bb = blockIdx.x;
  if (bb < 4096) {
    int i = (bb * 256 + threadIdx.x) * 8;
    const float4* p = reinterpret_cast<const float4*>(x + i);
    float4 a = p[0], b = p[1];
    f16x8 o;
    o[0] = (f16)a.x; o[1] = (f16)a.y; o[2] = (f16)a.z; o[3] = (f16)a.w;
    o[4] = (f16)b.x; o[5] = (f16)b.y; o[6] = (f16)b.z; o[7] = (f16)b.w;
    *reinterpret_cast<f16x8*>(xb + i) = o;
  } else if (bb < 6144) {
    int seg = (bb - 4096) >> 9;
    const float* in = (seg == 0) ? w0 : (seg == 1) ? w1 : (seg == 2) ? w2 : w3;
    f16* out = (seg == 0) ? o0 : (seg == 1) ? o1 : (seg == 2) ? o2 : o3;
    int i = (((bb - 4096) & 511) * 256 + threadIdx.x) * 8;
    const float4* p = reinterpret_cast<const float4*>(in + i);
    float4 a = p[0], b = p[1];
    f16x8 o;
    o[0] = (f16)a.x; o[1] = (f16)a.y; o[2] = (f16)a.z; o[3] = (f16)a.w;
    o[4] = (f16)b.x; o[5] = (f16)b.y; o[6] = (f16)b.z; o[7] = (f16)b.w;
    *reinterpret_cast<f16x8*>(out + i) = o;
  } else if (bb < 6400) {
    int E = *pE, skip = *pSkip;
    int idx = (bb - 6144) * 256 + threadIdx.x;
    int s = idx >> 5, t = idx & 31;
    float c = 1.0f, sn = 0.0f;
    if (!(skip && s < E)) {
      int p = skip ? s - E : s;
      float inv_freq = powf(10000.0f, -(float)t / 32.0f);
      sincosf((float)p * inv_freq, &sn, &c);
    }
    sctab[idx] = make_float2(c, sn);
  } else {
    int tid = threadIdx.x;
    int b = tid >> 6, jb = tid & 63;
    unsigned bits = 0;
    for (int j = 0; j < 32; ++j)
      bits |= (amask[b * 2048 + jb * 32 + j] != 0 ? 1u : 0u) << j;
    pmask[tid] = bits;
  }
}

// ---------------- GEMM: C[M,N] = A[M,K] * B[N,K]^T ----------------
// BK=64, 2 LDS buffers = 64 KB, counted-vmcnt depth-1 (r16-exact).
template<int MODE>
__global__ __launch_bounds__(256) void k_gemm(
    const f16* __restrict__ A,
    const f16* __restrict__ B0, const f16* __restrict__ B1, const f16* __restrict__ B2,
    void* __restrict__ C0, void* __restrict__ C1, void* __restrict__ C2,
    const float2* __restrict__ sctab) {
  constexpr int K = 1024, N = 1024;
  __shared__ char smem[65536];
  const int lid = blockIdx.x;
  const int xcd = lid & 7;
  int z, mp, n;
  if (MODE == 1) {
    int c = lid >> 3;
    mp = xcd * 8 + (c & 7);
    n = c >> 3;
    z = 0;
  } else {
    int c = lid >> 3;
    mp = xcd * 8 + (c & 7);
    n = (c >> 3) & 7;
    z = c >> 6;
  }
  const f16* B = (z == 0) ? B0 : ((z == 1) ? B1 : B2);
  const int tid = threadIdx.x;
  const int lane = tid & 63;
  const int wave = tid >> 6;
  const int wr = wave >> 1, wc = wave & 1;
  const int l15 = lane & 15, l4 = lane >> 4;
  const int m0 = mp * 128, n0 = n * 128;

  const int sr = tid >> 3, su = tid & 7;
  const int ce = (su ^ (sr & 7)) * 8;
  const f16* gA0 = A + (size_t)(m0 + sr) * K + ce;
  const f16* gB0 = B + (size_t)(n0 + sr) * K + ce;

  auto STAGE = [&](int bb, int kt) {
#pragma unroll
    for (int k = 0; k < 4; ++k)
      gload_lds16(gA0 + kt + (size_t)(32 * k) * K,
                  smem + bb * 16384 + k * 4096 + tid * 16);
#pragma unroll
    for (int k = 0; k < 4; ++k)
      gload_lds16(gB0 + kt + (size_t)(32 * k) * K,
                  smem + 32768 + bb * 16384 + k * 4096 + tid * 16);
  };

  f32x4 acc[4][4] = {};

  STAGE(0, 0);
  for (int t = 0; t < 16; ++t) {
    const int cur = t & 1;
    if (t + 1 < 16) {
      STAGE(cur ^ 1, (t + 1) * 64);
      asm volatile("s_waitcnt vmcnt(8)" ::: "memory");
    } else {
      asm volatile("s_waitcnt vmcnt(0)" ::: "memory");
    }
    __builtin_amdgcn_s_barrier();
    __builtin_amdgcn_sched_barrier(0);
#pragma unroll
    for (int kk = 0; kk < 2; ++kk) {
      f16x8 af[4], bf[4];
#pragma unroll
      for (int mi = 0; mi < 4; ++mi) {
        int r = wr * 64 + mi * 16 + l15;
        af[mi] = *reinterpret_cast<const f16x8*>(
            smem + cur * 16384 + r * 128 + (((kk * 4 + l4) ^ (r & 7)) * 16));
      }
#pragma unroll
      for (int ni = 0; ni < 4; ++ni) {
        int r = wc * 64 + ni * 16 + l15;
        bf[ni] = *reinterpret_cast<const f16x8*>(
            smem + 32768 + cur * 16384 + r * 128 + (((kk * 4 + l4) ^ (r & 7)) * 16));
      }
#pragma unroll
      for (int mi = 0; mi < 4; ++mi)
#pragma unroll
        for (int ni = 0; ni < 4; ++ni)
          acc[mi][ni] = __builtin_amdgcn_mfma_f32_16x16x32_f16(af[mi], bf[ni], acc[mi][ni], 0, 0, 0);
    }
  }

  if (MODE == 1) {
#pragma unroll
    for (int mi = 0; mi < 4; ++mi)
#pragma unroll
      for (int ni = 0; ni < 4; ++ni)
#pragma unroll
        for (int r = 0; r < 4; ++r) {
          int row = m0 + wr * 64 + mi * 16 + l4 * 4 + r;
          int col = n0 + wc * 64 + ni * 16 + l15;
          ((float*)C0)[(size_t)row * N + col] = acc[mi][ni][r];
        }
    return;
  }

  f16* Qf = (f16*)C0;
  f16* Kx = (f16*)C1;
  f16* Vx = (f16*)C2;

  if (z == 0) {
#pragma unroll
    for (int mi = 0; mi < 4; ++mi)
#pragma unroll
      for (int ni = 0; ni < 4; ++ni)
#pragma unroll
        for (int r = 0; r < 4; ++r) {
          int row = m0 + wr * 64 + mi * 16 + l4 * 4 + r;
          int col = n0 + wc * 64 + ni * 16 + l15;
          int s = row & 2047;
          int dd = col & 63;
          float val = acc[mi][ni][r];
          float pv = __shfl_xor(val, 1, 64);
          float2 cs = sctab[s * 32 + (dd >> 1)];
          val = val * cs.x + ((l15 & 1) ? pv * cs.y : -pv * cs.y);
          Qf[(size_t)row * 1024 + col] = (f16)val;
        }
    return;
  }

  __syncthreads();  // all loads landed; reuse smem as C-tile
  f16* Ct = (f16*)smem;

  if (z == 1) {
#pragma unroll
    for (int mi = 0; mi < 4; ++mi)
#pragma unroll
      for (int ni = 0; ni < 4; ++ni)
#pragma unroll
        for (int r = 0; r < 4; ++r) {
          int sl = wr * 64 + mi * 16 + l4 * 4 + r;
          int cl = wc * 64 + ni * 16 + l15;
          int s = (m0 + sl) & 2047;
          float val = acc[mi][ni][r];
          float pv = __shfl_xor(val, 1, 64);
          float2 cs = sctab[s * 32 + ((cl & 63) >> 1)];
          val = val * cs.x + ((l15 & 1) ? pv * cs.y : -pv * cs.y);
          *(f16*)((char*)Ct + sl * 256 + (((cl >> 3) ^ (sl & 15)) << 4) + (cl & 7) * 2) = (f16)val;
        }
    __syncthreads();
#pragma unroll
    for (int it = 0; it < 8; ++it) {
      int it2 = wave * 8 + it;
      int h2 = it2 >> 4, k16 = (it2 >> 2) & 3, hf = (it2 >> 1) & 1, sh = it2 & 1;
      int sl = sh * 64 + lane;
      int cl = h2 * 64 + k16 * 16 + hf * 8;
      f16x8 v = *(const f16x8*)((const char*)Ct + sl * 256 + (((cl >> 3) ^ (sl & 15)) << 4));
      int sg = m0 + sl;
      int b = sg >> 11, s = sg & 2047;
      int h = (n0 >> 6) + h2;
      *reinterpret_cast<f16x8*>(
          Kx + (((size_t)((b * 16 + h) * 4 + k16) * 2048 + s) << 4) + hf * 8) = v;
    }
  } else {
#pragma unroll
    for (int mi = 0; mi < 4; ++mi)
#pragma unroll
      for (int ni = 0; ni < 4; ++ni) {
        int sl = wr * 64 + mi * 16 + l4 * 4;
        int cl = wc * 64 + ni * 16 + l15;
        f16x4 pk;
#pragma unroll
        for (int r = 0; r < 4; ++r) pk[r] = (f16)acc[mi][ni][r];
        *(f16x4*)((char*)Ct + cl * 256 + ((((sl >> 2) ^ (cl & 31))) << 3)) = pk;
      }
    __syncthreads();
#pragma unroll
    for (int it = 0; it < 8; ++it) {
      int it2 = wave * 8 + it;
      int hh = it2 >> 4, dh2 = (it2 >> 3) & 1, kvb = (it2 >> 1) & 3, hf = it2 & 1;
      int kh = lane >> 5, ql = lane & 31;
      int cl = hh * 64 + dh2 * 32 + ql;
      int s0 = kvb * 32 + kh * 16 + hf * 4;
      f16x4 a = *(const f16x4*)((const char*)Ct + cl * 256 + (((s0 >> 2) ^ (cl & 31)) << 3));
      f16x4 c = *(const f16x4*)((const char*)Ct + cl * 256 + ((((s0 + 8) >> 2) ^ (cl & 31)) << 3));
      f16x8 v;
#pragma unroll
      for (int e = 0; e < 4; ++e) { v[e] = a[e]; v[4 + e] = c[e]; }
      int b = m0 >> 11;
      int kvblk = ((m0 & 2047) >> 5) + kvb;
      int h = (n0 >> 6) + hh;
      size_t idx = (((size_t)(((b * 16 + h) * 64 + kvblk) * 2 + dh2) * 2 + kh) * 32 + ql) << 4;
      *reinterpret_cast<f16x8*>(Vx + idx + hf * 8) = v;
    }
  }
}

// ---------------- flash attention: 8-wave Q-group, 2 blocks/CU -----------
// Grid 512 x 512 = 64 bh x 8 groups (r23 geometry: CU pairs get groups
// (7-t, t), 80 tiles/CU uniform). RACE FIX vs r23: the prefetch STAGE is
// issued AFTER the barrier. A wave can only pass barrier(jb) after its
// iter-(jb-1) MFMAs, which required lgkmcnt waits on that buffer's
// ds_reads -> when all waves pass the barrier, all reads of
// buf[(jb-1)%3] are complete, and only then is its overwrite issued.
// No timing-margin dependence (G16). vmcnt(1) keeps one prefetch in
// flight across the barrier (coverage ~1 iter; depth-2 was null in r22).
__global__ __launch_bounds__(512) void k_attn(
    const f16* __restrict__ Q, const f16* __restrict__ Kx, const f16* __restrict__ Vx,
    const unsigned* __restrict__ pmask, const int* __restrict__ pE,
    f16* __restrict__ AO) {
  __shared__ char smem[24576];   // 3 x [K 4KB | V 4KB]
  const int lid = (blockIdx.x & 7) * 64 + (blockIdx.x >> 3);  // XCD swizzle (512%8==0)
  const int local = lid & 63;
  const int bh = (lid >> 6) * 8 + (local & 7);                // 8 bh per XCD
  const int tG = local >> 3;
  const int G = (tG < 4) ? (7 - tG) : (tG - 4);               // heavy first; CU pairs sum 80
  const int tid = threadIdx.x;
  const int wave = tid >> 6;
  const int lane = tid & 63;
  const int ql = lane & 31;
  const int hf = lane >> 5;
  const int b = bh >> 4, h = bh & 15;
  const int E = *pE;
  const int ekv = (E + 31) >> 5;
  constexpr float SCALE = 0.125f * 1.44269504088896f;  // dh^-0.5 * log2(e)

  // staging: thread t fetches global unit u(lp)=(lp&31)*2+(lp>>5) of its
  // plane into linear LDS unit t -> fragment reads at lane*16, conflict-free.
  const char* sbase;
  int sstride, dstoff;
  {
    int lp = tid & 63;
    int su = ((lp & 31) * 2 + (lp >> 5)) * 16;
    if (tid < 256) {             // K: plane = tid>>6 (k16), 1KB/plane/jb
      int plane = tid >> 6;
      sbase = (const char*)Kx + ((size_t)(bh * 4 + plane) << 16) + su;
      sstride = 1024;
      dstoff = tid * 16;         // [0, 4096)
    } else {                     // V: plane = c (0..3), 1KB/plane, 4KB/jb
      int vt = tid - 256;
      int plane = vt >> 6;
      sbase = (const char*)Vx + (size_t)(bh * 64) * 4096 + plane * 1024 + su;
      sstride = 4096;
      dstoff = 4096 + vt * 16;   // [4096, 8192)
    }
  }

  auto STAGE = [&](int buf, int jb) {
    gload_lds16(sbase + (size_t)jb * sstride, smem + buf * 8192 + dstoff);
  };

  const int qt = 8 * G + wave;
  const int irow = qt * 32 + ql;
  int nkv_own = qt + 1;
  if (ekv > nkv_own) nkv_own = ekv;
  if (nkv_own > 64) nkv_own = 64;
  int nkv_blk = 8 * G + 8;
  if (ekv > nkv_blk) nkv_blk = ekv;
  if (nkv_blk > 64) nkv_blk = 64;

  f16x8 qf[4];
  {
    const f16* qp = Q + ((size_t)(b * 2048 + irow)) * 1024 + h * 64 + hf * 8;
#pragma unroll
    for (int k16 = 0; k16 < 4; ++k16) {
      f16x8 v = *reinterpret_cast<const f16x8*>(qp + k16 * 16);
#pragma unroll
      for (int e = 0; e < 8; ++e) v[e] = (f16)((float)v[e] * SCALE);
      qf[k16] = v;
    }
  }

  f32x16 acc0 = {}, acc1 = {};
  float mq = -1e30f, lq = 0.f;

  STAGE(0, 0);
  STAGE(1, 1);   // nkv_blk >= 8 always (G >= 0)
  for (int jb = 0; jb < nkv_blk; ++jb) {
    const int buf = jb % 3;
    if (jb + 1 < nkv_blk) {
      asm volatile("s_waitcnt vmcnt(1)" ::: "memory");
    } else {
      asm volatile("s_waitcnt vmcnt(0)" ::: "memory");
    }
    __builtin_amdgcn_s_barrier();
    __builtin_amdgcn_sched_barrier(0);
    // prefetch AFTER the barrier: all reads of buf[(jb+2)%3]=buf[(jb-1)%3]
    // are provably complete (see header comment) -> race-free.
    if (jb + 2 < nkv_blk) STAGE((jb + 2) % 3, jb + 2);
    if (jb < nkv_own) {
      const char* Ks = smem + buf * 8192;
      const char* Vs = Ks + 4096;
      __builtin_amdgcn_s_setprio(1);
      f32x16 st = {};
#pragma unroll
      for (int k16 = 0; k16 < 4; ++k16) {
        f16x8 kf = *reinterpret_cast<const f16x8*>(Ks + k16 * 1024 + lane * 16);
        st = __builtin_amdgcn_mfma_f32_32x32x16_f16(kf, qf[k16], st, 0, 0, 0);
      }
      __builtin_amdgcn_s_setprio(0);
      f16x8 vf[4];
#pragma unroll
      for (int c = 0; c < 4; ++c)
        vf[c] = *reinterpret_cast<const f16x8*>(Vs + c * 1024 + lane * 16);
      unsigned pm = pmask[b * 64 + jb];
      bool full = ((jb < qt) || ((jb + 1) * 32 <= E)) && (pm == 0xffffffffu);
      if (!full) {
#pragma unroll
        for (int r = 0; r < 16; ++r) {
          int kvl = (r & 3) + 8 * (r >> 2) + 4 * hf;
          int jcol = jb * 32 + kvl;
          bool vis = ((jcol <= irow) || (jcol < E)) && (((pm >> kvl) & 1u) != 0);
          st[r] = vis ? st[r] : -1e30f;
        }
      }
      float t0 = fmaxf(fmaxf(st[0], st[1]), st[2]);
      float t1 = fmaxf(fmaxf(st[3], st[4]), st[5]);
      float t2 = fmaxf(fmaxf(st[6], st[7]), st[8]);
      float t3 = fmaxf(fmaxf(st[9], st[10]), st[11]);
      float t4 = fmaxf(fmaxf(st[12], st[13]), st[14]);
      float mt = fmaxf(fmaxf(t0, t1), t2);
      mt = fmaxf(fmaxf(mt, t3), fmaxf(t4, st[15]));
      mt = fmaxf(mt, __shfl_xor(mt, 32, 64));
      if (!__all(mt - mq <= 8.0f)) {
        float mnew = fmaxf(mq, mt);
        float alpha = fexp2(mq - mnew);
        lq *= alpha;
#pragma unroll
        for (int r = 0; r < 16; ++r) { acc0[r] *= alpha; acc1[r] *= alpha; }
        mq = mnew;
      }
      union PF { unsigned u[4]; f16x8 v; } pf0, pf1;
#pragma unroll
      for (int t = 0; t < 4; ++t) {
        pf0.u[t] = __builtin_bit_cast(unsigned, __builtin_amdgcn_cvt_pkrtz(
            fexp2(st[2 * t] - mq), fexp2(st[2 * t + 1] - mq)));
        pf1.u[t] = __builtin_bit_cast(unsigned, __builtin_amdgcn_cvt_pkrtz(
            fexp2(st[8 + 2 * t] - mq), fexp2(st[9 + 2 * t] - mq)));
      }
      float ps = 0.f;
#pragma unroll
      for (int t = 0; t < 4; ++t) {
        ps = fdot2u(pf0.u[t], ONES2, ps);
        ps = fdot2u(pf1.u[t], ONES2, ps);
      }
      lq += ps;
      __builtin_amdgcn_s_setprio(1);
      acc0 = __builtin_amdgcn_mfma_f32_32x32x16_f16(vf[0], pf0.v, acc0, 0, 0, 0);
      acc0 = __builtin_amdgcn_mfma_f32_32x32x16_f16(vf[1], pf1.v, acc0, 0, 0, 0);
      acc1 = __builtin_amdgcn_mfma_f32_32x32x16_f16(vf[2], pf0.v, acc1, 0, 0, 0);
      acc1 = __builtin_amdgcn_mfma_f32_32x32x16_f16(vf[3], pf1.v, acc1, 0, 0, 0);
      __builtin_amdgcn_s_setprio(0);
    }
  }

  float ltot = lq + __shfl_xor(lq, 32, 64);
  float inv = 1.0f / ltot;
  f16* op = AO + ((size_t)(b * 2048 + irow)) * 1024 + h * 64;
#pragma unroll
  for (int t = 0; t < 4; ++t) {
    int d0 = 8 * t + 4 * hf;
    f16x4 o0, o1;
#pragma unroll
    for (int e = 0; e < 4; ++e) {
      o0[e] = (f16)(acc0[4 * t + e] * inv);
      o1[e] = (f16)(acc1[4 * t + e] * inv);
    }
    *reinterpret_cast<f16x4*>(op + d0) = o0;
    *reinterpret_cast<f16x4*>(op + 32 + d0) = o1;
  }
}

// ---------------- launcher ----------------
extern "C" void kernel_launch(void* const* d_in, const int* in_sizes, int n_in,
                              void* d_out, int out_size, void* d_ws, size_t ws_size,
                              hipStream_t stream) {
  const float* x  = (const float*)d_in[0];
  const float* Wq = (const float*)d_in[1];
  const float* Wk = (const float*)d_in[2];
  const float* Wv = (const float*)d_in[3];
  const float* Wo = (const float*)d_in[4];
  const int* amask = (const int*)d_in[5];
  const int* pE    = (const int*)d_in[6];
  const int* pSkip = (const int*)d_in[7];

  char* ws = (char*)d_ws;
  f16* xb   = (f16*)(ws);
  f16* Wqb  = (f16*)(ws + (16u << 20));
  f16* Wkb  = (f16*)(ws + (18u << 20));
  f16* Wvb  = (f16*)(ws + (20u << 20));
  f16* Wob  = (f16*)(ws + (22u << 20));
  f16* Qf   = (f16*)(ws + (24u << 20));
  f16* Kx   = (f16*)(ws + (40u << 20));
  f16* Vx   = (f16*)(ws + (56u << 20));
  float2* sctab = (float2*)(ws + (72u << 20));
  unsigned* pmask = (unsigned*)(ws + (73u << 20));
  f16* AO   = xb;

  k_prep<<<6401, 256, 0, stream>>>(x, Wq, Wk, Wv, Wo, xb, Wqb, Wkb, Wvb, Wob,
                                   amask, pE, pSkip, sctab, pmask);
  k_gemm<2><<<1536, 256, 0, stream>>>(xb, Wqb, Wkb, Wvb, Qf, Kx, Vx, sctab);
  k_attn<<<512, 512, 0, stream>>>(Qf, Kx, Vx, pmask, pE, AO);
  k_gemm<1><<<512, 256, 0, stream>>>(AO, Wob, Wob, Wob, d_out, d_out, d_out, nullptr);
}